// Round 1
// baseline (1035.267 us; speedup 1.0000x reference)
//
#include <hip/hip_runtime.h>
#include <math.h>

// CoAttentionLayer: B=128, Lq=Lk=512, QS=KS=256, AS=64, all fp32.
//
// rel = tanh((Q @ W_rel) @ K^T)            [B,512,512]  (strip-buffered, 32 batches)
// q_proj = Q @ W_q ; k_proj = K @ W_k      [B,512,64]
// q_logit = tanh(q_proj + rel @ k_proj) @ W_q_att    -> softmax over seq -> q_att_w
// k_logit = tanh(k_proj + rel^T @ q_proj) @ W_k_att  -> softmax over seq -> k_att_w
// out = [att_w * inputs, att_w...]
//
// ws budget: qw_buf 16MB + rel_buf 32MB + projections 33.5MB + logits 0.5MB = 84.4MB
// (strip processing keeps rel/qw buffers small; ws_size assumed >= 85MB < out bytes)

#define BATCH 128
#define SEQ   512
#define DIM   256
#define ADIM  64
#define SB    32          // batches per strip
#define NSTRIP 4

// ws offsets (floats)
#define OFF_QW    ((size_t)0)
#define OFF_REL   ((size_t)4194304)    // SB*512*256
#define OFF_QPROJ ((size_t)12582912)   // + SB*512*512
#define OFF_KPROJ ((size_t)16777216)   // + 128*512*64
#define OFF_QLOG  ((size_t)20971520)
#define OFF_KLOG  ((size_t)21037056)

// d_out offsets (floats)
#define OUT_WQ    ((size_t)0)
#define OUT_WK    ((size_t)16777216)
#define OUT_QATT  ((size_t)33554432)
#define OUT_KATT  ((size_t)33619968)

#define LDSS 68   // LDS row stride (pad 64 -> 68: keeps float4 16B-aligned, breaks pow2 banks)

// stage a 64x64 tile row-major: dst[r][c] = src[r*ld + c], dst stride LDSS
__device__ __forceinline__ void stage_rm(float* dst, const float* src, int ld) {
  const int t = threadIdx.x;
  const int r = t >> 4;
  const int c4 = (t & 15) << 2;
#pragma unroll
  for (int i = 0; i < 4; i++) {
    *(float4*)&dst[(r + 16 * i) * LDSS + c4] =
        *(const float4*)&src[(size_t)(r + 16 * i) * ld + c4];
  }
}

// stage a 64x64 tile transposed: dst[k][n] = src[n*ld + k], dst stride LDSS
__device__ __forceinline__ void stage_tr(float* dst, const float* src, int ld) {
  const int t = threadIdx.x;
  const int n = t >> 4;
  const int k4 = (t & 15) << 2;
#pragma unroll
  for (int i = 0; i < 4; i++) {
    float4 f = *(const float4*)&src[(size_t)(n + 16 * i) * ld + k4];
    dst[(k4 + 0) * LDSS + n + 16 * i] = f.x;
    dst[(k4 + 1) * LDSS + n + 16 * i] = f.y;
    dst[(k4 + 2) * LDSS + n + 16 * i] = f.z;
    dst[(k4 + 3) * LDSS + n + 16 * i] = f.w;
  }
}

#define FMA_ROW(ci, ai)                  \
  ci.x = fmaf(ai, b4.x, ci.x);           \
  ci.y = fmaf(ai, b4.y, ci.y);           \
  ci.z = fmaf(ai, b4.z, ci.z);           \
  ci.w = fmaf(ai, b4.w, ci.w);

#define GEMM_INNER_NN                                        \
  _Pragma("unroll 16")                                       \
  for (int kk = 0; kk < 64; kk++) {                          \
    float4 b4 = *(float4*)&sB[kk * LDSS + tn4];              \
    float a0 = sA[(tm4 + 0) * LDSS + kk];                    \
    float a1 = sA[(tm4 + 1) * LDSS + kk];                    \
    float a2 = sA[(tm4 + 2) * LDSS + kk];                    \
    float a3 = sA[(tm4 + 3) * LDSS + kk];                    \
    FMA_ROW(c0, a0) FMA_ROW(c1, a1) FMA_ROW(c2, a2) FMA_ROW(c3, a3) \
  }

// ---------------- generic NN gemm: C[M,N] = A[M,K] @ B[K,N] ----------------
__global__ __launch_bounds__(256) void gemm_nn(const float* __restrict__ Am, int lda,
                                               const float* __restrict__ Bm, int ldb,
                                               float* __restrict__ Cm, int ldc, int K) {
  __shared__ float sA[64 * LDSS];
  __shared__ float sB[64 * LDSS];
  const int m0 = blockIdx.x * 64;
  const int n0 = blockIdx.y * 64;
  const int t = threadIdx.x;
  const int tm4 = (t >> 4) << 2;
  const int tn4 = (t & 15) << 2;
  float4 c0 = {0, 0, 0, 0}, c1 = {0, 0, 0, 0}, c2 = {0, 0, 0, 0}, c3 = {0, 0, 0, 0};
  for (int k0 = 0; k0 < K; k0 += 64) {
    stage_rm(sA, Am + (size_t)m0 * lda + k0, lda);
    stage_rm(sB, Bm + (size_t)k0 * ldb + n0, ldb);
    __syncthreads();
    GEMM_INNER_NN
    __syncthreads();
  }
  *(float4*)&Cm[(size_t)(m0 + tm4 + 0) * ldc + n0 + tn4] = c0;
  *(float4*)&Cm[(size_t)(m0 + tm4 + 1) * ldc + n0 + tn4] = c1;
  *(float4*)&Cm[(size_t)(m0 + tm4 + 2) * ldc + n0 + tn4] = c2;
  *(float4*)&Cm[(size_t)(m0 + tm4 + 3) * ldc + n0 + tn4] = c3;
}

// ------------- rel = tanh(QW @ K^T), batched over strip -------------
__global__ __launch_bounds__(256) void rel_kernel(const float* __restrict__ QW,   // [SB*512,256]
                                                  const float* __restrict__ Kmat, // [SB*512,256]
                                                  float* __restrict__ Rel) {      // [SB,512,512]
  __shared__ float sA[64 * LDSS];
  __shared__ float sB[64 * LDSS];
  const int m0 = blockIdx.x * 64;  // q
  const int n0 = blockIdx.y * 64;  // k-seq
  const int b = blockIdx.z;
  const float* Ab = QW + (size_t)b * SEQ * DIM;
  const float* Bb = Kmat + (size_t)b * SEQ * DIM;
  float* Cb = Rel + (size_t)b * SEQ * SEQ;
  const int t = threadIdx.x;
  const int tm4 = (t >> 4) << 2;
  const int tn4 = (t & 15) << 2;
  float4 c0 = {0, 0, 0, 0}, c1 = {0, 0, 0, 0}, c2 = {0, 0, 0, 0}, c3 = {0, 0, 0, 0};
  for (int k0 = 0; k0 < DIM; k0 += 64) {
    stage_rm(sA, Ab + (size_t)m0 * DIM + k0, DIM);
    stage_tr(sB, Bb + (size_t)n0 * DIM + k0, DIM);  // sB[d][kseq] = K[kseq][d]
    __syncthreads();
    GEMM_INNER_NN
    __syncthreads();
  }
  float4 r0, r1, r2, r3;
  r0.x = tanhf(c0.x); r0.y = tanhf(c0.y); r0.z = tanhf(c0.z); r0.w = tanhf(c0.w);
  r1.x = tanhf(c1.x); r1.y = tanhf(c1.y); r1.z = tanhf(c1.z); r1.w = tanhf(c1.w);
  r2.x = tanhf(c2.x); r2.y = tanhf(c2.y); r2.z = tanhf(c2.z); r2.w = tanhf(c2.w);
  r3.x = tanhf(c3.x); r3.y = tanhf(c3.y); r3.z = tanhf(c3.z); r3.w = tanhf(c3.w);
  *(float4*)&Cb[(size_t)(m0 + tm4 + 0) * SEQ + n0 + tn4] = r0;
  *(float4*)&Cb[(size_t)(m0 + tm4 + 1) * SEQ + n0 + tn4] = r1;
  *(float4*)&Cb[(size_t)(m0 + tm4 + 2) * SEQ + n0 + tn4] = r2;
  *(float4*)&Cb[(size_t)(m0 + tm4 + 3) * SEQ + n0 + tn4] = r3;
}

// ---- q side: logit[q] = (tanh(q_proj + rel @ k_proj) @ W_q_att) ----
__global__ __launch_bounds__(256) void qacc_kernel(const float* __restrict__ Rel,    // [SB,512,512]
                                                   const float* __restrict__ kproj,  // [128*512,64]
                                                   const float* __restrict__ qproj,  // [128*512,64]
                                                   const float* __restrict__ Watt,   // [64]
                                                   float* __restrict__ logit,        // [128*512]
                                                   int gb0) {
  __shared__ float sA[64 * LDSS];
  __shared__ float sB[64 * LDSS];
  const int m0 = blockIdx.x * 64;  // q rows
  const int b = blockIdx.y;
  const int gb = gb0 + b;
  const float* Ab = Rel + (size_t)b * SEQ * SEQ;
  const float* Bb = kproj + (size_t)gb * SEQ * ADIM;
  const int t = threadIdx.x;
  const int tm4 = (t >> 4) << 2;
  const int tn4 = (t & 15) << 2;
  float4 c0 = {0, 0, 0, 0}, c1 = {0, 0, 0, 0}, c2 = {0, 0, 0, 0}, c3 = {0, 0, 0, 0};
  for (int k0 = 0; k0 < SEQ; k0 += 64) {
    stage_rm(sA, Ab + (size_t)m0 * SEQ + k0, SEQ);
    stage_rm(sB, Bb + (size_t)k0 * ADIM, ADIM);
    __syncthreads();
    GEMM_INNER_NN
    __syncthreads();
  }
  // epilogue: score = tanh(q_proj + acc); partial = score . Watt ; reduce over 16 lanes
  const float* P = qproj + (size_t)gb * SEQ * ADIM;
  float4 w4 = *(const float4*)&Watt[tn4];
  float part[4];
  float4 cc[4] = {c0, c1, c2, c3};
#pragma unroll
  for (int i = 0; i < 4; i++) {
    float4 p = *(const float4*)&P[(size_t)(m0 + tm4 + i) * ADIM + tn4];
    float sx = tanhf(p.x + cc[i].x);
    float sy = tanhf(p.y + cc[i].y);
    float sz = tanhf(p.z + cc[i].z);
    float sw = tanhf(p.w + cc[i].w);
    part[i] = sx * w4.x + sy * w4.y + sz * w4.z + sw * w4.w;
  }
#pragma unroll
  for (int off = 8; off; off >>= 1) {
#pragma unroll
    for (int i = 0; i < 4; i++) part[i] += __shfl_down(part[i], off, 16);
  }
  if ((t & 15) == 0) {
#pragma unroll
    for (int i = 0; i < 4; i++) logit[(size_t)gb * SEQ + m0 + tm4 + i] = part[i];
  }
}

// ---- k side: logit[k] = (tanh(k_proj + rel^T @ q_proj) @ W_k_att) ----
__global__ __launch_bounds__(256) void kacc_kernel(const float* __restrict__ Rel,
                                                   const float* __restrict__ qproj,
                                                   const float* __restrict__ kproj,
                                                   const float* __restrict__ Watt,
                                                   float* __restrict__ logit,
                                                   int gb0) {
  __shared__ float sA[64 * LDSS];  // sA[qlocal][kseq]  (rel rows are already [q][kseq])
  __shared__ float sB[64 * LDSS];
  const int m0 = blockIdx.x * 64;  // k-seq rows
  const int b = blockIdx.y;
  const int gb = gb0 + b;
  const float* Ab = Rel + (size_t)b * SEQ * SEQ;
  const float* Bb = qproj + (size_t)gb * SEQ * ADIM;
  const int t = threadIdx.x;
  const int tm4 = (t >> 4) << 2;
  const int tn4 = (t & 15) << 2;
  float4 c0 = {0, 0, 0, 0}, c1 = {0, 0, 0, 0}, c2 = {0, 0, 0, 0}, c3 = {0, 0, 0, 0};
  for (int q0 = 0; q0 < SEQ; q0 += 64) {
    // sA[kk][m] = rel[q0+kk][m0+m] : direct row-major copy of rel rows
    stage_rm(sA, Ab + (size_t)q0 * SEQ + m0, SEQ);
    stage_rm(sB, Bb + (size_t)q0 * ADIM, ADIM);
    __syncthreads();
#pragma unroll 16
    for (int kk = 0; kk < 64; kk++) {
      float4 a4 = *(float4*)&sA[kk * LDSS + tm4];
      float4 b4 = *(float4*)&sB[kk * LDSS + tn4];
      FMA_ROW(c0, a4.x) FMA_ROW(c1, a4.y) FMA_ROW(c2, a4.z) FMA_ROW(c3, a4.w)
    }
    __syncthreads();
  }
  const float* P = kproj + (size_t)gb * SEQ * ADIM;
  float4 w4 = *(const float4*)&Watt[tn4];
  float part[4];
  float4 cc[4] = {c0, c1, c2, c3};
#pragma unroll
  for (int i = 0; i < 4; i++) {
    float4 p = *(const float4*)&P[(size_t)(m0 + tm4 + i) * ADIM + tn4];
    float sx = tanhf(p.x + cc[i].x);
    float sy = tanhf(p.y + cc[i].y);
    float sz = tanhf(p.z + cc[i].z);
    float sw = tanhf(p.w + cc[i].w);
    part[i] = sx * w4.x + sy * w4.y + sz * w4.z + sw * w4.w;
  }
#pragma unroll
  for (int off = 8; off; off >>= 1) {
#pragma unroll
    for (int i = 0; i < 4; i++) part[i] += __shfl_down(part[i], off, 16);
  }
  if ((t & 15) == 0) {
#pragma unroll
    for (int i = 0; i < 4; i++) logit[(size_t)gb * SEQ + m0 + tm4 + i] = part[i];
  }
}

// ---- softmax over seq dim, writes att_w straight into d_out ----
__global__ __launch_bounds__(256) void softmax_kernel(const float* __restrict__ qlog,
                                                      const float* __restrict__ klog,
                                                      float* __restrict__ out) {
  const int bx = blockIdx.x;  // 0..255
  const int side = bx >> 7;
  const int b = bx & 127;
  const float* lg = (side ? klog : qlog) + (size_t)b * SEQ;
  float* o = out + OUT_QATT + (size_t)side * (BATCH * SEQ) + (size_t)b * SEQ;
  const int t = threadIdx.x;
  float v0 = lg[t];
  float v1 = lg[t + 256];
  float m = fmaxf(v0, v1);
#pragma unroll
  for (int off = 32; off; off >>= 1) m = fmaxf(m, __shfl_xor(m, off));
  __shared__ float sm[4], ss[4];
  const int w = t >> 6, l = t & 63;
  if (l == 0) sm[w] = m;
  __syncthreads();
  m = fmaxf(fmaxf(sm[0], sm[1]), fmaxf(sm[2], sm[3]));
  float e0 = expf(v0 - m), e1 = expf(v1 - m);
  float s = e0 + e1;
#pragma unroll
  for (int off = 32; off; off >>= 1) s += __shfl_xor(s, off);
  if (l == 0) ss[w] = s;
  __syncthreads();
  s = ss[0] + ss[1] + ss[2] + ss[3];
  float inv = 1.0f / s;
  o[t] = e0 * inv;
  o[t + 256] = e1 * inv;
}

// ---- weighted_* = att_w * inputs ----
__global__ __launch_bounds__(256) void weight_kernel(const float* __restrict__ queries,
                                                     const float* __restrict__ keys,
                                                     float* __restrict__ out) {
  const size_t g = (size_t)blockIdx.x * 256 + threadIdx.x;  // float4 index, 8,388,608 total
  const int side = (int)(g >> 22);                          // 4,194,304 float4 per side
  const size_t loc = g & 4194303;
  const size_t row = loc >> 6;  // 64 float4 per row of 256 floats
  const float* aw = out + OUT_QATT + (size_t)side * (BATCH * SEQ);
  const float4* src = (const float4*)(side ? keys : queries);
  const float w = aw[row];
  float4 v = src[loc];
  float4 r = {v.x * w, v.y * w, v.z * w, v.w * w};
  ((float4*)out)[g] = r;
}

extern "C" void kernel_launch(void* const* d_in, const int* in_sizes, int n_in,
                              void* d_out, int out_size, void* d_ws, size_t ws_size,
                              hipStream_t stream) {
  const float* queries = (const float*)d_in[0];
  const float* keys = (const float*)d_in[1];
  const float* w_rel = (const float*)d_in[2];
  const float* W_q = (const float*)d_in[3];
  const float* W_k = (const float*)d_in[4];
  const float* W_qa = (const float*)d_in[5];
  const float* W_ka = (const float*)d_in[6];
  float* out = (float*)d_out;
  float* ws = (float*)d_ws;

  float* qw_buf = ws + OFF_QW;
  float* rel_buf = ws + OFF_REL;
  float* q_proj = ws + OFF_QPROJ;
  float* k_proj = ws + OFF_KPROJ;
  float* q_log = ws + OFF_QLOG;
  float* k_log = ws + OFF_KLOG;

  // projections: [65536,256] @ [256,64]
  gemm_nn<<<dim3(1024, 1), 256, 0, stream>>>(queries, DIM, W_q, ADIM, q_proj, ADIM, DIM);
  gemm_nn<<<dim3(1024, 1), 256, 0, stream>>>(keys, DIM, W_k, ADIM, k_proj, ADIM, DIM);

  for (int s = 0; s < NSTRIP; s++) {
    const int gb0 = s * SB;
    const float* Qs = queries + (size_t)gb0 * SEQ * DIM;
    const float* Ks = keys + (size_t)gb0 * SEQ * DIM;
    // qw_buf = Q_strip @ w_relation : [16384,256] @ [256,256]
    gemm_nn<<<dim3(256, 4), 256, 0, stream>>>(Qs, DIM, w_rel, DIM, qw_buf, DIM, DIM);
    // rel_buf = tanh(qw_buf @ K_strip^T) batched
    rel_kernel<<<dim3(8, 8, SB), 256, 0, stream>>>(qw_buf, Ks, rel_buf);
    // logits
    qacc_kernel<<<dim3(8, SB), 256, 0, stream>>>(rel_buf, k_proj, q_proj, W_qa, q_log, gb0);
    kacc_kernel<<<dim3(8, SB), 256, 0, stream>>>(rel_buf, q_proj, k_proj, W_ka, k_log, gb0);
  }

  softmax_kernel<<<256, 256, 0, stream>>>(q_log, k_log, out);
  weight_kernel<<<32768, 256, 0, stream>>>(queries, keys, out);
}

// Round 3
// 424.295 us; speedup vs baseline: 2.4400x; 2.4400x over previous
//
#include <hip/hip_runtime.h>
#include <math.h>

// CoAttentionLayer fp16-MFMA pipeline. B=128, L=512, D=256, A=64.
// (Round 2 was bf16: absmax 1.1e-3 vs 8.06e-4 threshold. fp16 has 8x finer
// quantization at the same MFMA rate -> predicted absmax ~3e-4.)
//
//  cvt:   Q,K -> fp16; w_rel^T, W_q^T, W_k^T -> fp16 (transposed, K-major)
//  proj:  qp = Qh@Wq, kp = Kh@Wk  (fp16 row-major + per-batch transposed copies)
//  per strip of 64 batches (scratch in d_out's weighted_* region, which is
//  only written by the FINAL weight kernel):
//    qw  = Qh@w_rel                      [strip*512, 256] fp16
//    rel = tanh(qw @ Kh^T)  (+ rel^T)    [64,512,512] fp16 each
//    qlogit = (tanh(qp + rel @ kp) @ W_qa)      fused epilogue
//    klogit = (tanh(kp + rel^T @ qp) @ W_ka)    fused epilogue
//  softmax over seq -> att weights (d_out tail region)
//  weighted outputs = att_w * inputs (overwrites scratch region last)
//
// ws layout (shorts): Qh 16.78M | Kh 16.78M | qp 4.19M | kp 4.19M | qlog/klog f32
//   total = 84,410,368 B. d_out scratch ends at 100.86MB < att region @134.2MB.

#define SEQ 512
#define DIM 256
#define ADIM 64
#define OUT_QATT ((size_t)33554432)  // float offset of q_att_w in d_out

using hfrag = __attribute__((ext_vector_type(8))) _Float16;
using s4 = __attribute__((ext_vector_type(4))) short;
using f4 = __attribute__((ext_vector_type(4))) float;
typedef unsigned int u32;

__device__ __forceinline__ void gl_lds16(const short* g, short* l) {
  __builtin_amdgcn_global_load_lds((const __attribute__((address_space(1))) u32*)g,
                                   (__attribute__((address_space(3))) u32*)l, 16, 0, 0);
}

__device__ __forceinline__ short f2h(float x) {  // fp32 -> fp16 RNE bit pattern
  _Float16 h = (_Float16)x;
  return __builtin_bit_cast(short, h);
}
__device__ __forceinline__ float h2f(short s) {
  return (float)__builtin_bit_cast(_Float16, s);
}
__device__ __forceinline__ float tanhf_fast(float x) {
  float e = __expf(2.0f * x);
  return 1.0f - 2.0f / (e + 1.0f);
}

// ---------------- MFMA cores ----------------
// C = A @ Bt^T.  A: [>=tileM, KTOT] K-major fp16, pre-offset to tile row 0.
// Bt: [>=tileN, KTOT] K-major, pre-offset.  LDS cols XOR-swizzled by row&7.
// 256 threads = 4 waves.

template <int KTOT>
__device__ __forceinline__ void core128(const short* __restrict__ A,
                                        const short* __restrict__ Bt,
                                        short* sA, short* sB, f4 acc[4][4]) {
  const int t = threadIdx.x;
  const int lane = t & 63, wave = t >> 6;
  const int wm = (wave & 1) << 6, wn = (wave >> 1) << 6;
  const int l15 = lane & 15, qd = lane >> 4;
  const int srow = t >> 3, scol = (t & 7) << 3;
  for (int k0 = 0; k0 < KTOT; k0 += 64) {
#pragma unroll
    for (int i = 0; i < 4; i++) {
      const int row = srow + (i << 5);
      const int gcol = k0 + (scol ^ ((row & 7) << 3));
      gl_lds16(&A[(size_t)row * KTOT + gcol], &sA[t * 8 + i * 2048]);
      gl_lds16(&Bt[(size_t)row * KTOT + gcol], &sB[t * 8 + i * 2048]);
    }
    __syncthreads();
#pragma unroll
    for (int ks = 0; ks < 2; ks++) {
      hfrag af[4], bg[4];
      const int kk = (ks << 5) + (qd << 3);
#pragma unroll
      for (int i = 0; i < 4; i++) {
        const int ar = wm + (i << 4) + l15;
        const int br = wn + (i << 4) + l15;
        af[i] = *(const hfrag*)&sA[(ar << 6) + (kk ^ ((ar & 7) << 3))];
        bg[i] = *(const hfrag*)&sB[(br << 6) + (kk ^ ((br & 7) << 3))];
      }
#pragma unroll
      for (int i = 0; i < 4; i++)
#pragma unroll
        for (int j = 0; j < 4; j++)
          acc[i][j] = __builtin_amdgcn_mfma_f32_16x16x32_f16(af[i], bg[j], acc[i][j], 0, 0, 0);
    }
    __syncthreads();
  }
}

template <int KTOT>
__device__ __forceinline__ void core64(const short* __restrict__ A,
                                       const short* __restrict__ Bt,
                                       short* sA, short* sB, f4 acc[4][2]) {
  const int t = threadIdx.x;
  const int lane = t & 63, wave = t >> 6;
  const int wm = (wave & 1) << 6, wn = (wave >> 1) << 5;
  const int l15 = lane & 15, qd = lane >> 4;
  const int srow = t >> 3, scol = (t & 7) << 3;
  for (int k0 = 0; k0 < KTOT; k0 += 64) {
#pragma unroll
    for (int i = 0; i < 4; i++) {
      const int row = srow + (i << 5);
      const int gcol = k0 + (scol ^ ((row & 7) << 3));
      gl_lds16(&A[(size_t)row * KTOT + gcol], &sA[t * 8 + i * 2048]);
      if (i < 2) gl_lds16(&Bt[(size_t)row * KTOT + gcol], &sB[t * 8 + i * 2048]);
    }
    __syncthreads();
#pragma unroll
    for (int ks = 0; ks < 2; ks++) {
      hfrag af[4], bg[2];
      const int kk = (ks << 5) + (qd << 3);
#pragma unroll
      for (int i = 0; i < 4; i++) {
        const int ar = wm + (i << 4) + l15;
        af[i] = *(const hfrag*)&sA[(ar << 6) + (kk ^ ((ar & 7) << 3))];
      }
#pragma unroll
      for (int j = 0; j < 2; j++) {
        const int br = wn + (j << 4) + l15;
        bg[j] = *(const hfrag*)&sB[(br << 6) + (kk ^ ((br & 7) << 3))];
      }
#pragma unroll
      for (int i = 0; i < 4; i++)
#pragma unroll
        for (int j = 0; j < 2; j++)
          acc[i][j] = __builtin_amdgcn_mfma_f32_16x16x32_f16(af[i], bg[j], acc[i][j], 0, 0, 0);
    }
    __syncthreads();
  }
}

// ---------------- kernels ----------------

// inputs -> fp16; small weights transposed+converted
__global__ __launch_bounds__(256) void cvt_kernel(const float* __restrict__ Q,
                                                  const float* __restrict__ K,
                                                  const float* __restrict__ wrel,
                                                  const float* __restrict__ Wq,
                                                  const float* __restrict__ Wk,
                                                  short* __restrict__ Qh, short* __restrict__ Kh,
                                                  short* __restrict__ wrelT,
                                                  short* __restrict__ WqT,
                                                  short* __restrict__ WkT) {
  const int bid = blockIdx.x;
  if (bid < 32768) {
    const size_t g = ((size_t)bid << 8) + threadIdx.x;  // float4 idx, 8,388,608 total
    const int side = (int)(g >> 22);
    const size_t loc = g & 4194303;
    const float4 v = ((const float4*)(side ? K : Q))[loc];
    s4 o;
    o[0] = f2h(v.x); o[1] = f2h(v.y); o[2] = f2h(v.z); o[3] = f2h(v.w);
    *(s4*)&(side ? Kh : Qh)[loc << 2] = o;
  } else {
    const int b2 = bid - 32768;
    if (b2 < 64) {  // wrelT[e*256+d] = wrel[d*256+e], 65536 elems
      const int i = (b2 << 8) + threadIdx.x;
#pragma unroll
      for (int u = 0; u < 4; u++) {
        const int idx = (i << 2) + u;
        const int e = idx >> 8, d = idx & 255;
        wrelT[idx] = f2h(wrel[(d << 8) + e]);
      }
    } else if (b2 < 72) {  // WqT[a*256+d] = Wq[d*64+a], 16384 elems
      const int i = ((b2 - 64) << 8) + threadIdx.x;
#pragma unroll
      for (int u = 0; u < 8; u++) {
        const int idx = (i << 3) + u;
        const int a = idx >> 8, d = idx & 255;
        WqT[idx] = f2h(Wq[(d << 6) + a]);
      }
    } else if (b2 < 80) {
      const int i = ((b2 - 72) << 8) + threadIdx.x;
#pragma unroll
      for (int u = 0; u < 8; u++) {
        const int idx = (i << 3) + u;
        const int a = idx >> 8, d = idx & 255;
        WkT[idx] = f2h(Wk[(d << 6) + a]);
      }
    }
  }
}

// qp/kp = X @ W  (tile 128x64, K=256); writes row-major + per-batch transposed
__global__ __launch_bounds__(256) void proj_kernel(const short* __restrict__ Qh,
                                                   const short* __restrict__ Kh,
                                                   const short* __restrict__ WqT,
                                                   const short* __restrict__ WkT,
                                                   short* __restrict__ qp, short* __restrict__ kp,
                                                   short* __restrict__ qpT, short* __restrict__ kpT) {
  __shared__ short sA[8192];
  __shared__ short sB[4096];
  const int which = blockIdx.y;
  const short* A = which ? Kh : Qh;
  const short* Bt = which ? WkT : WqT;
  short* P = which ? kp : qp;
  short* PT = which ? kpT : qpT;
  const int m0 = blockIdx.x << 7;
  f4 acc[4][2];
  const f4 fz = {0.f, 0.f, 0.f, 0.f};
#pragma unroll
  for (int i = 0; i < 4; i++)
#pragma unroll
    for (int j = 0; j < 2; j++) acc[i][j] = fz;
  core64<256>(A + (size_t)m0 * 256, Bt, sA, sB, acc);
  const int lane = threadIdx.x & 63, wave = threadIdx.x >> 6;
  const int wm = (wave & 1) << 6, wn = (wave >> 1) << 5;
  const int l15 = lane & 15, qd = lane >> 4;
#pragma unroll
  for (int i = 0; i < 4; i++)
#pragma unroll
    for (int j = 0; j < 2; j++) {
      s4 pack;
      const int gm0 = m0 + wm + (i << 4) + (qd << 2);
      const int a = wn + (j << 4) + l15;
#pragma unroll
      for (int r = 0; r < 4; r++) {
        pack[r] = f2h(acc[i][j][r]);
        P[(size_t)(gm0 + r) * ADIM + a] = pack[r];
      }
      const int bb = gm0 >> 9, ql = gm0 & 511;
      *(s4*)&PT[((size_t)bb * ADIM + a) * SEQ + ql] = pack;
    }
}

// qw = Qh(strip) @ w_rel  (tile 128x128, K=256)
__global__ __launch_bounds__(256) void qw_kernel(const short* __restrict__ Qh,
                                                 const short* __restrict__ WrT,
                                                 short* __restrict__ qw) {
  __shared__ short sA[8192];
  __shared__ short sB[8192];
  const int m0 = blockIdx.x << 7, n0 = blockIdx.y << 7;
  f4 acc[4][4];
  const f4 fz = {0.f, 0.f, 0.f, 0.f};
#pragma unroll
  for (int i = 0; i < 4; i++)
#pragma unroll
    for (int j = 0; j < 4; j++) acc[i][j] = fz;
  core128<256>(Qh + (size_t)m0 * 256, WrT + (size_t)n0 * 256, sA, sB, acc);
  const int lane = threadIdx.x & 63, wave = threadIdx.x >> 6;
  const int wm = (wave & 1) << 6, wn = (wave >> 1) << 6;
  const int l15 = lane & 15, qd = lane >> 4;
#pragma unroll
  for (int i = 0; i < 4; i++)
#pragma unroll
    for (int j = 0; j < 4; j++)
#pragma unroll
      for (int r = 0; r < 4; r++) {
        const int row = m0 + wm + (i << 4) + (qd << 2) + r;
        const int col = n0 + wn + (j << 4) + l15;
        qw[(size_t)row * 256 + col] = f2h(acc[i][j][r]);
      }
}

// rel = tanh(qw @ Kh^T) per batch; writes rel + rel^T (fp16)
__global__ __launch_bounds__(256) void rel_mfma(const short* __restrict__ qw,
                                                const short* __restrict__ Kh,
                                                short* __restrict__ rel,
                                                short* __restrict__ relT) {
  __shared__ short sA[8192];
  __shared__ short sB[8192];
  const int b = blockIdx.z;
  const int m0 = blockIdx.x << 7, n0 = blockIdx.y << 7;
  f4 acc[4][4];
  const f4 fz = {0.f, 0.f, 0.f, 0.f};
#pragma unroll
  for (int i = 0; i < 4; i++)
#pragma unroll
    for (int j = 0; j < 4; j++) acc[i][j] = fz;
  core128<256>(qw + ((size_t)b * SEQ + m0) * 256, Kh + ((size_t)b * SEQ + n0) * 256, sA, sB, acc);
  short* R = rel + (size_t)b * SEQ * SEQ;
  short* RT = relT + (size_t)b * SEQ * SEQ;
  const int lane = threadIdx.x & 63, wave = threadIdx.x >> 6;
  const int wm = (wave & 1) << 6, wn = (wave >> 1) << 6;
  const int l15 = lane & 15, qd = lane >> 4;
#pragma unroll
  for (int i = 0; i < 4; i++)
#pragma unroll
    for (int j = 0; j < 4; j++) {
      s4 pack;
      const int row0 = m0 + wm + (i << 4) + (qd << 2);
      const int col = n0 + wn + (j << 4) + l15;
#pragma unroll
      for (int r = 0; r < 4; r++) {
        pack[r] = f2h(tanhf_fast(acc[i][j][r]));
        R[(size_t)(row0 + r) * SEQ + col] = pack[r];
      }
      *(s4*)&RT[(size_t)col * SEQ + row0] = pack;
    }
}

// logit[m] = sum_a tanh(proj[m,a] + (A @ Pt^T)[m,a]) * Watt[a]
// qacc: A=rel,  Pt=kpT, proj=qp ; kacc: A=relT, Pt=qpT, proj=kp
__global__ __launch_bounds__(256) void acc_kernel(const short* __restrict__ Rel,
                                                  const short* __restrict__ Pt,
                                                  const short* __restrict__ Prm,
                                                  const float* __restrict__ Watt,
                                                  float* __restrict__ logit, int gb0) {
  __shared__ short sA[8192];
  __shared__ short sB[4096];
  __shared__ float lbuf[128][2];
  const int b = blockIdx.y, gb = gb0 + b;
  const int m0 = blockIdx.x << 7;
  f4 acc[4][2];
  const f4 fz = {0.f, 0.f, 0.f, 0.f};
#pragma unroll
  for (int i = 0; i < 4; i++)
#pragma unroll
    for (int j = 0; j < 2; j++) acc[i][j] = fz;
  core64<512>(Rel + (size_t)b * SEQ * SEQ + (size_t)m0 * SEQ, Pt + (size_t)gb * ADIM * SEQ,
              sA, sB, acc);
  const int lane = threadIdx.x & 63, wave = threadIdx.x >> 6;
  const int wm = (wave & 1) << 6, wn = (wave >> 1) << 5;
  const int l15 = lane & 15, qd = lane >> 4;
  float p[4][4];
#pragma unroll
  for (int i = 0; i < 4; i++)
#pragma unroll
    for (int r = 0; r < 4; r++) p[i][r] = 0.f;
#pragma unroll
  for (int i = 0; i < 4; i++)
#pragma unroll
    for (int r = 0; r < 4; r++) {
      const int gm = gb * SEQ + m0 + wm + (i << 4) + (qd << 2) + r;
#pragma unroll
      for (int j = 0; j < 2; j++) {
        const int a = wn + (j << 4) + l15;
        const float s = tanhf_fast(h2f(Prm[(size_t)gm * ADIM + a]) + acc[i][j][r]);
        p[i][r] += s * Watt[a];
      }
    }
#pragma unroll
  for (int off = 8; off; off >>= 1)
#pragma unroll
    for (int i = 0; i < 4; i++)
#pragma unroll
      for (int r = 0; r < 4; r++) p[i][r] += __shfl_down(p[i][r], off, 16);
  if (l15 == 0) {
#pragma unroll
    for (int i = 0; i < 4; i++)
#pragma unroll
      for (int r = 0; r < 4; r++) lbuf[wm + (i << 4) + (qd << 2) + r][wave >> 1] = p[i][r];
  }
  __syncthreads();
  const int t = threadIdx.x;
  if (t < 128) logit[(size_t)gb * SEQ + m0 + t] = lbuf[t][0] + lbuf[t][1];
}

// softmax over seq dim -> att weights in d_out tail
__global__ __launch_bounds__(256) void softmax_kernel(const float* __restrict__ qlog,
                                                      const float* __restrict__ klog,
                                                      float* __restrict__ out) {
  const int bx = blockIdx.x;  // 0..255
  const int side = bx >> 7;
  const int b = bx & 127;
  const float* lg = (side ? klog : qlog) + (size_t)b * SEQ;
  float* o = out + OUT_QATT + (size_t)side * (128 * SEQ) + (size_t)b * SEQ;
  const int t = threadIdx.x;
  float v0 = lg[t];
  float v1 = lg[t + 256];
  float m = fmaxf(v0, v1);
#pragma unroll
  for (int off = 32; off; off >>= 1) m = fmaxf(m, __shfl_xor(m, off));
  __shared__ float sm[4], ss[4];
  const int w = t >> 6, l = t & 63;
  if (l == 0) sm[w] = m;
  __syncthreads();
  m = fmaxf(fmaxf(sm[0], sm[1]), fmaxf(sm[2], sm[3]));
  float e0 = expf(v0 - m), e1 = expf(v1 - m);
  float s = e0 + e1;
#pragma unroll
  for (int off = 32; off; off >>= 1) s += __shfl_xor(s, off);
  if (l == 0) ss[w] = s;
  __syncthreads();
  s = ss[0] + ss[1] + ss[2] + ss[3];
  float inv = 1.0f / s;
  o[t] = e0 * inv;
  o[t + 256] = e1 * inv;
}

// weighted_* = att_w * inputs (runs LAST: overwrites the scratch region)
__global__ __launch_bounds__(256) void weight_kernel(const float* __restrict__ queries,
                                                     const float* __restrict__ keys,
                                                     float* __restrict__ out) {
  const size_t g = (size_t)blockIdx.x * 256 + threadIdx.x;  // float4 index
  const int side = (int)(g >> 22);
  const size_t loc = g & 4194303;
  const size_t row = loc >> 6;
  const float* aw = out + OUT_QATT + (size_t)side * (128 * SEQ);
  const float4* src = (const float4*)(side ? keys : queries);
  const float w = aw[row];
  float4 v = src[loc];
  float4 r = {v.x * w, v.y * w, v.z * w, v.w * w};
  ((float4*)out)[g] = r;
}

extern "C" void kernel_launch(void* const* d_in, const int* in_sizes, int n_in,
                              void* d_out, int out_size, void* d_ws, size_t ws_size,
                              hipStream_t stream) {
  const float* queries = (const float*)d_in[0];
  const float* keys = (const float*)d_in[1];
  const float* w_rel = (const float*)d_in[2];
  const float* W_q = (const float*)d_in[3];
  const float* W_k = (const float*)d_in[4];
  const float* W_qa = (const float*)d_in[5];
  const float* W_ka = (const float*)d_in[6];
  float* out = (float*)d_out;

  // ws layout (shorts / floats)
  short* Qh = (short*)d_ws;
  short* Kh = Qh + 16777216;
  short* qp = Kh + 16777216;
  short* kp = qp + 4194304;
  float* qlog = (float*)(kp + 4194304);
  float* klog = qlog + 65536;

  // d_out scratch (safe until weight_kernel; att region starts at byte 134,217,728)
  char* ob = (char*)d_out;
  short* rel_s = (short*)ob;
  short* relT_s = (short*)(ob + 33554432);
  short* qw_s = (short*)(ob + 67108864);
  short* qpT = (short*)(ob + 83886080);
  short* kpT = (short*)(ob + 92274688);
  short* wrelT = (short*)(ob + 100663296);
  short* WqT = (short*)(ob + 100794368);
  short* WkT = (short*)(ob + 100827136);

  cvt_kernel<<<32848, 256, 0, stream>>>(queries, keys, w_rel, W_q, W_k, Qh, Kh, wrelT, WqT, WkT);
  proj_kernel<<<dim3(512, 2), 256, 0, stream>>>(Qh, Kh, WqT, WkT, qp, kp, qpT, kpT);

  for (int s = 0; s < 2; s++) {
    const int gb0 = s * 64;
    qw_kernel<<<dim3(256, 2), 256, 0, stream>>>(Qh + (size_t)gb0 * SEQ * DIM, wrelT, qw_s);
    rel_mfma<<<dim3(4, 4, 64), 256, 0, stream>>>(qw_s, Kh + (size_t)gb0 * SEQ * DIM, rel_s, relT_s);
    acc_kernel<<<dim3(4, 64), 256, 0, stream>>>(rel_s, kpT, qp, W_qa, qlog, gb0);
    acc_kernel<<<dim3(4, 64), 256, 0, stream>>>(relT_s, qpT, kp, W_ka, klog, gb0);
  }

  softmax_kernel<<<256, 256, 0, stream>>>(qlog, klog, out);
  weight_kernel<<<32768, 256, 0, stream>>>(queries, keys, out);
}